// Round 16
// baseline (474.605 us; speedup 1.0000x reference)
//
#include <hip/hip_runtime.h>
#include <math.h>

// SGD filter design: 999 sequential SGD steps on one SOS section (all 16
// provably identical). Round 16 = round-15 + reciprocal batching:
// rcp(x),rcp(y) -> rP=rcp(x*y); 1/x=y*rP; 1/y=x*rP.
//  - tanh pair: 2 rcp -> 1 rcp + 3 mul
//  - per-freq rnb/rna quad: 4 rcp -> 1 rcp + 9 mul
// Trans ops/iter: 12 -> 8 (trans issue at ~16cy dominates the wave's stream).

typedef float v2 __attribute__((ext_vector_type(2)));

// LR * K * C * 8  (K = 6.020599913279624, C = 0.033929256398692726)
#define LRK8_ 3.2683916458e-5f
// 1/(8K)
#define INVK8_ 0.020762050593046017f

__device__ __forceinline__ float rcp_(float x)  { return __builtin_amdgcn_rcpf(x); }
__device__ __forceinline__ float rsq_(float x)  { return __builtin_amdgcn_rsqf(x); }
__device__ __forceinline__ float log2_(float x) { return __builtin_amdgcn_logf(x); }
__device__ __forceinline__ float exp2_(float x) { return __builtin_amdgcn_exp2f(x); }

template <int CTRL>
__device__ __forceinline__ float dpp_add(float x) {
    int y = __builtin_amdgcn_update_dpp(0, __float_as_int(x), CTRL, 0xF, 0xF, true);
    return x + __int_as_float(y);
}

// Full 64-lane sum; result valid at lane 63.
__device__ __forceinline__ float wave_sum_at63(float x) {
    x = dpp_add<0x111>(x);  // row_shr:1
    x = dpp_add<0x112>(x);  // row_shr:2
    x = dpp_add<0x114>(x);  // row_shr:4
    x = dpp_add<0x118>(x);  // row_shr:8
    x = dpp_add<0x142>(x);  // row_bcast:15
    x = dpp_add<0x143>(x);  // row_bcast:31
    return x;
}

__device__ __forceinline__ float readlane_f(float x, int l) {
    return __int_as_float(__builtin_amdgcn_readlane(__float_as_int(x), l));
}

__global__ __launch_bounds__(256) void sgd_filter_kernel(const float* __restrict__ tgt,
                                                         float* __restrict__ out) {
    const int tid  = threadIdx.x;      // 0..255
    const int lane = tid & 63;
    const int wv   = tid >> 6;         // wave 0..3

    // two frequencies per lane, packed: element0 = tid, element1 = tid+256
    const float wA = (float)(3.14159265358979323846 * (double)tid / 511.0);
    const float wB = (float)(3.14159265358979323846 * (double)(tid + 256) / 511.0);
    float s1a, c1a, s1b, c1b;
    sincosf(wA, &s1a, &c1a);
    sincosf(wB, &s1b, &c1b);
    const v2 C1 = {c1a, c1b};
    const v2 S1 = {s1a, s1b};
    const v2 C2 = {c1a * c1a - s1a * s1a, c1b * c1b - s1b * s1b};
    const v2 S2 = {2.0f * c1a * s1a, 2.0f * c1b * s1b};
    // TKC = LRK8 * tg/(8K): cF = fma(LRK8, lg, -TKC)
    const v2 TKC = {tgt[tid] * (INVK8_ * LRK8_), tgt[tid + 256] * (INVK8_ * LRK8_)};

    // lane-replicated parameters, packed {p, z}
    float q0 = 1.0f;                 // g = q0 + 1
    v2 qr = {1.0f, 1.0f};            // {qpr, qzr}
    v2 qi = {1.0f, 1.0f};            // {qpi, qzi}

    __shared__ float part[2][32];    // [pp][wv*8 + l], l = 0..4

    const int widx = wv << 3;
    const int ridx = (((lane & 3) << 3) | (lane >> 2)) & 31; // lanes 0..19 useful

    for (int it = 0; it < 999; ++it) {
        // ---- uniform forward, packed {p,z} ----
        float g = q0 + 1.0f;
        v2 d2 = qr * qr + qi * qi;
        v2 iu = {rsq_(d2.x), rsq_(d2.y)};           // 1/|.|
        v2 u  = d2 * iu;                            // |.|
        v2 ea = u * 2.8853900817779268f;            // 2/ln2
        v2 e  = {exp2_(ea.x), exp2_(ea.y)};
        v2 e1 = e + 1.0f;
        float rE = rcp_(e1.x * e1.y);               // batched reciprocal pair
        v2 re = {e1.y * rE, e1.x * rE};
        v2 t  = 1.0f - 2.0f * re;                   // {tanh pu, tanh zu}
        v2 sc = t * iu;
        v2 rs = qr * sc;                            // {prs, zrs}
        v2 is = qi * sc;                            // {pis, zis}

        float zq = t.y * t.y;                       // zrs^2+zis^2
        float g2 = 2.0f * g;
        float b0 = g;
        float b1 = -g2 * rs.y;
        float b2 = g * zq;
        float a1 = -2.0f * rs.x;
        float a2 = t.x * t.x;

        // hoisted off the post-S tail (depends only on t, iu)
        v2 dsiu = (((1.0f - t * t) - t * iu) * iu) * iu;
        v2 gg2  = {2.0f, g2};

        // ---- per-frequency forward + adjoint, both freqs packed ----
        v2 Br = b0 + b1 * C1 + b2 * C2;
        v2 Bi = -(b1 * S1 + b2 * S2);
        v2 Ar = 1.0f + a1 * C1 + a2 * C2;
        v2 Ai = -(a1 * S1 + a2 * S2);
        v2 nb = Br * Br + Bi * Bi;
        v2 na = Ar * Ar + Ai * Ai;
        // batched reciprocal quad: one v_rcp for rnb.x, rnb.y, rna.x, rna.y
        float pxy = nb.x * nb.y;
        float axy = na.x * na.y;
        float rQ  = rcp_(pxy * axy);
        float arQ = axy * rQ;                       // 1/(nb.x*nb.y)
        float prQ = pxy * rQ;                       // 1/(na.x*na.y)
        v2 rnb = {nb.y * arQ, nb.x * arQ};
        v2 rna = {na.y * prQ, na.x * prQ};
        v2 r  = nb * rna;
        v2 lg = {log2_(r.x), log2_(r.y)};
        v2 cF = LRK8_ * lg - TKC;                   // single packed fma
        v2 cb = cF * rnb;
        v2 ca = cF * rna;
        v2 cbBr = cb * Br, cbBi = cb * Bi;
        v2 caAr = ca * Ar, caAi = ca * Ai;
        v2 gb1v = cbBr * C1 - cbBi * S1;
        v2 gb2v = cbBr * C2 - cbBi * S2;
        v2 ga1v = caAr * C1 - caAi * S1;
        v2 ga2v = caAr * C2 - caAi * S2;

        // ---- horizontal + in-wave DPP sums (valid at lane 63) ----
        float t0 = wave_sum_at63(cbBr.x + cbBr.y);
        float t1 = wave_sum_at63(gb1v.x + gb1v.y);
        float t2 = wave_sum_at63(gb2v.x + gb2v.y);
        float t3 = wave_sum_at63(-(ga1v.x + ga1v.y));
        float t4 = wave_sum_at63(-(ga2v.x + ga2v.y));

        const int pp = it & 1;
        if (lane == 63) {
            float* pb = &part[pp][widx];
            pb[0] = t0; pb[1] = t1; pb[2] = t2; pb[3] = t3; pb[4] = t4;
        }
        __syncthreads();

        // ---- cross-wave: groups of 4 ----
        float y = part[pp][ridx];
        y = dpp_add<0x111>(y);
        y = dpp_add<0x112>(y);
        float S0  = readlane_f(y, 3);
        float Sb1 = readlane_f(y, 7);
        float Sb2 = readlane_f(y, 11);
        float Sa1 = readlane_f(y, 15);
        float Sa2 = readlane_f(y, 19);

        // ---- uniform backward, packed {p,z} (LR folded into cF) ----
        float dg = S0 - 2.0f * rs.y * Sb1 + zq * Sb2;
        v2 S42 = {Sa2, Sb2};
        v2 S31 = {Sa1, Sb1};
        v2 dr = gg2 * (rs * S42 - S31);             // {dpr, dzr}
        v2 di = gg2 * (is * S42);                   // {dpi, dzi}
        v2 dotv = qr * dr + qi * di;
        v2 com = dsiu * dotv;
        v2 gqr = sc * dr + qr * com;
        v2 gqi = sc * di + qi * com;

        q0 -= dg;
        qr -= gqr;
        qi -= gqi;
    }

    // ---- final pz_to_sos, 16 identical sections ----
    {
        float g = q0 + 1.0f;
        v2 d2 = qr * qr + qi * qi;
        v2 iu = {rsq_(d2.x), rsq_(d2.y)};
        v2 u  = d2 * iu;
        v2 ea = u * 2.8853900817779268f;
        v2 e  = {exp2_(ea.x), exp2_(ea.y)};
        v2 e1 = e + 1.0f;
        v2 re = {rcp_(e1.x), rcp_(e1.y)};
        v2 t  = 1.0f - 2.0f * re;
        v2 sc = t * iu;
        v2 rs = qr * sc;
        float b0 = g;
        float b1 = -2.0f * g * rs.y;
        float b2 = g * (t.y * t.y);
        float a1 = -2.0f * rs.x;
        float a2 = t.x * t.x;
        if (tid < 96) {
            int c = tid % 6;
            float v = (c == 0) ? b0 : (c == 1) ? b1 : (c == 2) ? b2
                    : (c == 3) ? 1.0f : (c == 4) ? a1 : a2;
            out[tid] = v;
        }
    }
}

extern "C" void kernel_launch(void* const* d_in, const int* in_sizes, int n_in,
                              void* d_out, int out_size, void* d_ws, size_t ws_size,
                              hipStream_t stream) {
    (void)in_sizes; (void)n_in; (void)d_ws; (void)ws_size; (void)out_size;
    const float* tgt = (const float*)d_in[0];
    float* out = (float*)d_out;
    hipLaunchKernelGGL(sgd_filter_kernel, dim3(1), dim3(256), 0, stream, tgt, out);
}

// Round 17
// 454.865 us; speedup vs baseline: 1.0434x; 1.0434x over previous
//
#include <hip/hip_runtime.h>
#include <math.h>

// SGD filter design: 999 sequential SGD steps on one SOS section (all 16
// provably identical). Round 17 = exact revert to round 15 (best: 409us).
// Structure: 256 thr = 4 waves (1/SIMD), 2 freqs/lane packed <2 x float>,
// DPP wave reduction, 1 barrier + 1 ds_read/iter, eps-free loss path,
// v_rsq norms, independent (pipelined) v_rcp's — r16's rcp-batching
// regressed by serializing the trans chain.

typedef float v2 __attribute__((ext_vector_type(2)));

// LR * K * C * 8  (K = 6.020599913279624, C = 0.033929256398692726)
#define LRK8_ 3.2683916458e-5f
// 1/(8K)
#define INVK8_ 0.020762050593046017f

__device__ __forceinline__ float rcp_(float x)  { return __builtin_amdgcn_rcpf(x); }
__device__ __forceinline__ float rsq_(float x)  { return __builtin_amdgcn_rsqf(x); }
__device__ __forceinline__ float log2_(float x) { return __builtin_amdgcn_logf(x); }
__device__ __forceinline__ float exp2_(float x) { return __builtin_amdgcn_exp2f(x); }

template <int CTRL>
__device__ __forceinline__ float dpp_add(float x) {
    int y = __builtin_amdgcn_update_dpp(0, __float_as_int(x), CTRL, 0xF, 0xF, true);
    return x + __int_as_float(y);
}

// Full 64-lane sum; result valid at lane 63.
__device__ __forceinline__ float wave_sum_at63(float x) {
    x = dpp_add<0x111>(x);  // row_shr:1
    x = dpp_add<0x112>(x);  // row_shr:2
    x = dpp_add<0x114>(x);  // row_shr:4
    x = dpp_add<0x118>(x);  // row_shr:8
    x = dpp_add<0x142>(x);  // row_bcast:15
    x = dpp_add<0x143>(x);  // row_bcast:31
    return x;
}

__device__ __forceinline__ float readlane_f(float x, int l) {
    return __int_as_float(__builtin_amdgcn_readlane(__float_as_int(x), l));
}

__global__ __launch_bounds__(256) void sgd_filter_kernel(const float* __restrict__ tgt,
                                                         float* __restrict__ out) {
    const int tid  = threadIdx.x;      // 0..255
    const int lane = tid & 63;
    const int wv   = tid >> 6;         // wave 0..3

    // two frequencies per lane, packed: element0 = tid, element1 = tid+256
    const float wA = (float)(3.14159265358979323846 * (double)tid / 511.0);
    const float wB = (float)(3.14159265358979323846 * (double)(tid + 256) / 511.0);
    float s1a, c1a, s1b, c1b;
    sincosf(wA, &s1a, &c1a);
    sincosf(wB, &s1b, &c1b);
    const v2 C1 = {c1a, c1b};
    const v2 S1 = {s1a, s1b};
    const v2 C2 = {c1a * c1a - s1a * s1a, c1b * c1b - s1b * s1b};
    const v2 S2 = {2.0f * c1a * s1a, 2.0f * c1b * s1b};
    // TKC = LRK8 * tg/(8K): cF = fma(LRK8, lg, -TKC)
    const v2 TKC = {tgt[tid] * (INVK8_ * LRK8_), tgt[tid + 256] * (INVK8_ * LRK8_)};

    // lane-replicated parameters, packed {p, z}
    float q0 = 1.0f;                 // g = q0 + 1
    v2 qr = {1.0f, 1.0f};            // {qpr, qzr}
    v2 qi = {1.0f, 1.0f};            // {qpi, qzi}

    __shared__ float part[2][32];    // [pp][wv*8 + l], l = 0..4

    const int widx = wv << 3;
    const int ridx = (((lane & 3) << 3) | (lane >> 2)) & 31; // lanes 0..19 useful

    for (int it = 0; it < 999; ++it) {
        // ---- uniform forward, packed {p,z} ----
        float g = q0 + 1.0f;
        v2 d2 = qr * qr + qi * qi;
        v2 iu = {rsq_(d2.x), rsq_(d2.y)};           // 1/|.| directly
        v2 u  = d2 * iu;                            // |.| = d2 * rsq(d2)
        v2 ea = u * 2.8853900817779268f;            // 2/ln2
        v2 e  = {exp2_(ea.x), exp2_(ea.y)};
        v2 e1 = e + 1.0f;
        v2 re = {rcp_(e1.x), rcp_(e1.y)};
        v2 t  = 1.0f - 2.0f * re;                   // {tanh pu, tanh zu}
        v2 sc = t * iu;
        v2 rs = qr * sc;                            // {prs, zrs}
        v2 is = qi * sc;                            // {pis, zis}

        float zq = t.y * t.y;                       // zrs^2+zis^2
        float g2 = 2.0f * g;
        float b0 = g;
        float b1 = -g2 * rs.y;
        float b2 = g * zq;
        float a1 = -2.0f * rs.x;
        float a2 = t.x * t.x;

        // hoisted off the post-S tail (depends only on t, iu)
        v2 dsiu = (((1.0f - t * t) - t * iu) * iu) * iu;
        v2 gg2  = {2.0f, g2};

        // ---- per-frequency forward + adjoint, both freqs packed ----
        v2 Br = b0 + b1 * C1 + b2 * C2;
        v2 Bi = -(b1 * S1 + b2 * S2);
        v2 Ar = 1.0f + a1 * C1 + a2 * C2;
        v2 Ai = -(a1 * S1 + a2 * S2);
        v2 nb = Br * Br + Bi * Bi;
        v2 na = Ar * Ar + Ai * Ai;
        v2 rnb = {rcp_(nb.x), rcp_(nb.y)};
        v2 rna = {rcp_(na.x), rcp_(na.y)};
        v2 r  = nb * rna;
        v2 lg = {log2_(r.x), log2_(r.y)};
        v2 cF = LRK8_ * lg - TKC;                   // single packed fma
        v2 cb = cF * rnb;
        v2 ca = cF * rna;
        v2 cbBr = cb * Br, cbBi = cb * Bi;
        v2 caAr = ca * Ar, caAi = ca * Ai;
        v2 gb1v = cbBr * C1 - cbBi * S1;
        v2 gb2v = cbBr * C2 - cbBi * S2;
        v2 ga1v = caAr * C1 - caAi * S1;
        v2 ga2v = caAr * C2 - caAi * S2;

        // ---- horizontal + in-wave DPP sums (valid at lane 63) ----
        float t0 = wave_sum_at63(cbBr.x + cbBr.y);
        float t1 = wave_sum_at63(gb1v.x + gb1v.y);
        float t2 = wave_sum_at63(gb2v.x + gb2v.y);
        float t3 = wave_sum_at63(-(ga1v.x + ga1v.y));
        float t4 = wave_sum_at63(-(ga2v.x + ga2v.y));

        const int pp = it & 1;
        if (lane == 63) {
            float* pb = &part[pp][widx];
            pb[0] = t0; pb[1] = t1; pb[2] = t2; pb[3] = t3; pb[4] = t4;
        }
        __syncthreads();

        // ---- cross-wave: groups of 4 ----
        float y = part[pp][ridx];
        y = dpp_add<0x111>(y);
        y = dpp_add<0x112>(y);
        float S0  = readlane_f(y, 3);
        float Sb1 = readlane_f(y, 7);
        float Sb2 = readlane_f(y, 11);
        float Sa1 = readlane_f(y, 15);
        float Sa2 = readlane_f(y, 19);

        // ---- uniform backward, packed {p,z} (LR folded into cF) ----
        float dg = S0 - 2.0f * rs.y * Sb1 + zq * Sb2;
        v2 S42 = {Sa2, Sb2};
        v2 S31 = {Sa1, Sb1};
        v2 dr = gg2 * (rs * S42 - S31);             // {dpr, dzr}
        v2 di = gg2 * (is * S42);                   // {dpi, dzi}
        v2 dotv = qr * dr + qi * di;
        v2 com = dsiu * dotv;
        v2 gqr = sc * dr + qr * com;
        v2 gqi = sc * di + qi * com;

        q0 -= dg;
        qr -= gqr;
        qi -= gqi;
    }

    // ---- final pz_to_sos, 16 identical sections ----
    {
        float g = q0 + 1.0f;
        v2 d2 = qr * qr + qi * qi;
        v2 iu = {rsq_(d2.x), rsq_(d2.y)};
        v2 u  = d2 * iu;
        v2 ea = u * 2.8853900817779268f;
        v2 e  = {exp2_(ea.x), exp2_(ea.y)};
        v2 e1 = e + 1.0f;
        v2 re = {rcp_(e1.x), rcp_(e1.y)};
        v2 t  = 1.0f - 2.0f * re;
        v2 sc = t * iu;
        v2 rs = qr * sc;
        float b0 = g;
        float b1 = -2.0f * g * rs.y;
        float b2 = g * (t.y * t.y);
        float a1 = -2.0f * rs.x;
        float a2 = t.x * t.x;
        if (tid < 96) {
            int c = tid % 6;
            float v = (c == 0) ? b0 : (c == 1) ? b1 : (c == 2) ? b2
                    : (c == 3) ? 1.0f : (c == 4) ? a1 : a2;
            out[tid] = v;
        }
    }
}

extern "C" void kernel_launch(void* const* d_in, const int* in_sizes, int n_in,
                              void* d_out, int out_size, void* d_ws, size_t ws_size,
                              hipStream_t stream) {
    (void)in_sizes; (void)n_in; (void)d_ws; (void)ws_size; (void)out_size;
    const float* tgt = (const float*)d_in[0];
    float* out = (float*)d_out;
    hipLaunchKernelGGL(sgd_filter_kernel, dim3(1), dim3(256), 0, stream, tgt, out);
}